// Round 10
// baseline (468.676 us; speedup 1.0000x reference)
//
#include <hip/hip_runtime.h>
#include <hip/hip_bf16.h>
#include <cstdint>
#include <cstddef>

#define HDIM 64
#define EPS 1e-5f
#define BN 128                     // nodes per bucket
#define BSH 7
#define NXCD 8
#define BCAPX 2560                 // entries per (bucket,xcd) region (>= any bucket total)
#define CURPAD 16                  // u32 stride between cursors: one 64B line each
#define SENTE 128u                 // sentinel entry: msg row 0, loc=128 (dummy row)

typedef short bf16x8 __attribute__((ext_vector_type(8)));
typedef float f32x4  __attribute__((ext_vector_type(4)));
typedef float f4v    __attribute__((ext_vector_type(4)));
typedef unsigned u2v __attribute__((ext_vector_type(2)));
typedef unsigned u4v __attribute__((ext_vector_type(4)));

__device__ __forceinline__ unsigned bf16rn(float f) {
    unsigned u = __float_as_uint(f);
    return (u + 0x7FFFu + ((u >> 16) & 1u)) >> 16;   // round-nearest-even
}

// flipped bf16: monotone u16 encoding of bf16 order
__device__ __forceinline__ unsigned flipbf(float f) {
    unsigned h = bf16rn(f);
    return (h & 0x8000u) ? (~h & 0xFFFFu) : (h | 0x8000u);
}

// key = flip16 << 16 ; key==0 means "never touched" (all real keys have bits set)
__device__ __forceinline__ unsigned unflipkey(unsigned key) {
    if (key == 0u) return 0u;                         // empty -> bf16 zero
    unsigned k = key >> 16;
    return (k & 0x8000u) ? (k & 0x7FFFu) : (~k & 0xFFFFu);
}

// ---------------- fused prep: convert msg->flipped-bf16 || bucket fill || W prep --------
// Block-role split so the atomic-latency-bound fill and the VALU-light W prep
// hide under the streaming convert's HBM time (same dispatch = true overlap).
__global__ __launch_bounds__(256) void prep_kernel(
    const float* __restrict__ msg, unsigned short* __restrict__ msgB,
    const int* __restrict__ ei, unsigned* __restrict__ bcur,
    unsigned* __restrict__ entries,
    const float* __restrict__ W1, const float* __restrict__ W2,
    unsigned short* __restrict__ W1T, unsigned short* __restrict__ W2T,
    int E, int nblk, int cblocks, int eblocks) {
    int blk = blockIdx.x;
    if (blk < cblocks) {
        // ---- convert: 8 f32 -> 8 flipped-bf16 per thread ----
        size_t i = ((size_t)blk * 256 + threadIdx.x) * 8;
        size_t total = (size_t)E * HDIM;
        if (i < total) {
            f4v a = __builtin_nontemporal_load((const f4v*)&msg[i]);
            f4v b = __builtin_nontemporal_load((const f4v*)&msg[i + 4]);
            u4v o;
            o.x = flipbf(a.x) | (flipbf(a.y) << 16);
            o.y = flipbf(a.z) | (flipbf(a.w) << 16);
            o.z = flipbf(b.x) | (flipbf(b.y) << 16);
            o.w = flipbf(b.z) | (flipbf(b.w) << 16);
            __builtin_nontemporal_store(o, (u4v*)&msgB[i]);
        }
    } else if (blk < cblocks + eblocks) {
        // ---- bucket fill (XCD-local regions, line-private cursors) ----
        int e = (blk - cblocks) * 256 + threadIdx.x;
        if (e >= E) return;
        unsigned xcd;
        asm volatile("s_getreg_b32 %0, hwreg(HW_REG_XCC_ID)" : "=s"(xcd));
        xcd &= (NXCD - 1);
        int row = ei[e];
        int col = ei[(size_t)E + e];
        unsigned cell1 = (unsigned)(col >> BSH) * NXCD + xcd;
        unsigned cell2 = (unsigned)(nblk + (row >> BSH)) * NXCD + xcd;
        unsigned p1 = atomicAdd(&bcur[(size_t)cell1 * CURPAD], 1u);
        unsigned p2 = atomicAdd(&bcur[(size_t)cell2 * CURPAD], 1u);
        if (p1 < BCAPX)
            entries[(size_t)cell1 * BCAPX + p1] = ((unsigned)e << 8) | (unsigned)(col & (BN - 1));
        if (p2 < BCAPX)
            entries[(size_t)cell2 * BCAPX + p2] = ((unsigned)e << 8) | (unsigned)(row & (BN - 1));
    } else {
        // ---- W prep: W1T[o][k]=bf16(W1[k][o]), W2T likewise ----
        int t = (blk - cblocks - eblocks) * 256 + threadIdx.x;
        if (t < 128 * 64) {
            int k = t >> 6, o = t & 63;
            W1T[o * 128 + k] = (unsigned short)bf16rn(W1[t]);
        } else {
            int t2 = t - 128 * 64;
            if (t2 < 64 * 64) {
                int k = t2 >> 6, o = t2 & 63;
                W2T[o * 64 + k] = (unsigned short)bf16rn(W2[t2]);
            }
        }
    }
}

// ---------------- binned max via LDS ds_max_u32 on flipped-bf16 keys ----------------
// One WG (4 waves) per bucket, 33 KB LDS -> 4 WG/CU (16 waves). acc[129][64]
// u32 keys (flip16<<16), init 0 (= empty; every real key is nonzero).
// 2 B/lane loads (128 B/row wave transaction); ds_max is fire-and-forget.
__global__ __launch_bounds__(256) void binned_max_kernel(
    const unsigned short* __restrict__ msgB, const unsigned* __restrict__ bcur,
    const unsigned* __restrict__ entries,
    unsigned short* __restrict__ fwdB, unsigned short* __restrict__ bwdB,
    int N, int nblk) {
    __shared__ __align__(16) unsigned acc[(BN + 1) * HDIM];   // 33,024 B
    int tid = threadIdx.x;
    int wave = tid >> 6, lane = tid & 63;
    int b = blockIdx.x;

    {
        u4v z = {};
        u4v* p = (u4v*)acc;
        for (int i = tid; i < (BN + 1) * HDIM / 4; i += 256) p[i] = z;
    }
    __syncthreads();

    unsigned accBase = (unsigned)(size_t)&acc[0];   // low 32 bits of flat = LDS offset
    unsigned laneOff = accBase + ((unsigned)lane << 2);

    for (int rr = 0; rr < 2; ++rr) {
        int r = wave + rr * 4;
        unsigned cnt = bcur[((size_t)b * NXCD + r) * CURPAD];
        if (cnt > BCAPX) cnt = BCAPX;
        const unsigned* rb = entries + ((size_t)b * NXCD + r) * BCAPX;
        for (unsigned c0 = 0; c0 < cnt; c0 += 64) {
            unsigned myent = (c0 + (unsigned)lane < cnt) ? rb[c0 + lane] : SENTE;
            unsigned rem = cnt - c0;
#pragma unroll
            for (int b16 = 0; b16 < 4; ++b16) {
                if ((unsigned)(b16 * 16) >= rem) break;
                unsigned short v[16];
#pragma unroll
                for (int k = 0; k < 16; ++k) {
                    unsigned ent = __shfl(myent, b16 * 16 + k);
                    v[k] = __builtin_nontemporal_load(&msgB[(size_t)(ent >> 8) * HDIM + lane]);
                }
#pragma unroll
                for (int k = 0; k < 16; ++k) {
                    unsigned ent = __shfl(myent, b16 * 16 + k);
                    unsigned addr = laneOff + ((ent & 255u) << 8);   // (sl*64+lane)*4
                    unsigned key = ((unsigned)v[k]) << 16;
                    asm volatile("ds_max_u32 %0, %1" :: "v"(addr), "v"(key));
                }
            }
        }
    }
    asm volatile("" ::: "memory");   // compiler fence: acc modified by asm
    __syncthreads();                  // waits lgkmcnt(0): all ds_max complete

    // unflip keys -> bf16, empty -> 0, coalesced 8B writes
    bool fwd = (b < nblk);
    int node0 = (fwd ? b : b - nblk) * BN;
    unsigned short* dst = fwd ? fwdB : bwdB;
    for (int i = tid; i < BN * (HDIM / 4); i += 256) {   // 8 iters
        int rrow = i >> 4, c4 = (i & 15) * 4;
        int node = node0 + rrow;
        if (node >= N) continue;
        uint4 a = *(const uint4*)&acc[rrow * HDIM + c4];
        u2v o;
        o.x = unflipkey(a.x) | (unflipkey(a.y) << 16);
        o.y = unflipkey(a.z) | (unflipkey(a.w) << 16);
        *(u2v*)(dst + (size_t)node * HDIM + c4) = o;
    }
}

// ---------------- MLP (MFMA bf16) ----------------

// y1 = concat(fwd,bwd) @ W1 + b1, fused column stats.
// mfma_f32_16x16x32_bf16: A row=lane&15,k=(lane>>4)*8+j ; C/D col=lane&15,row=(lane>>4)*4+reg
__global__ __launch_bounds__(256) void gemm1_mfma_kernel(
    const unsigned short* __restrict__ fwdB, const unsigned short* __restrict__ bwdB,
    const unsigned short* __restrict__ W1T, const float* __restrict__ b1,
    float* __restrict__ y1, float* __restrict__ sum1, float* __restrict__ sq1, int N) {
    __shared__ float wsum[4][64], wsq[4][64];
    int tid = threadIdx.x;
    int wave = tid >> 6, lane = tid & 63;
    int lrow = lane & 15, kseg = lane >> 4;
    int rbase = blockIdx.x * 64 + wave * 16;

    bf16x8 bfr[4][4];
#pragma unroll
    for (int nt = 0; nt < 4; ++nt)
#pragma unroll
        for (int kb = 0; kb < 4; ++kb)
            bfr[nt][kb] = *(const bf16x8*)(W1T + (size_t)(nt * 16 + lrow) * 128 + kb * 32 + kseg * 8);

    int r = rbase + lrow;
    bool ok = (r < N);
    size_t ro = (size_t)(ok ? r : 0) * HDIM;
    bf16x8 z = {};
    bf16x8 afr[4];
    afr[0] = *(const bf16x8*)(fwdB + ro + kseg * 8);
    afr[1] = *(const bf16x8*)(fwdB + ro + 32 + kseg * 8);
    afr[2] = *(const bf16x8*)(bwdB + ro + kseg * 8);
    afr[3] = *(const bf16x8*)(bwdB + ro + 32 + kseg * 8);
    if (!ok) { afr[0] = z; afr[1] = z; afr[2] = z; afr[3] = z; }

    f32x4 acc[4] = {};
#pragma unroll
    for (int kb = 0; kb < 4; ++kb)
#pragma unroll
        for (int nt = 0; nt < 4; ++nt)
            acc[nt] = __builtin_amdgcn_mfma_f32_16x16x32_bf16(afr[kb], bfr[nt][kb], acc[nt], 0, 0, 0);

#pragma unroll
    for (int nt = 0; nt < 4; ++nt) {
        int col = nt * 16 + lrow;
        float bias = b1[col];
        float s = 0.f, q = 0.f;
#pragma unroll
        for (int rr = 0; rr < 4; ++rr) {
            int rowi = rbase + kseg * 4 + rr;
            if (rowi < N) {
                float v = acc[nt][rr] + bias;
                y1[(size_t)rowi * HDIM + col] = v;
                s += v; q += v * v;
            }
        }
        s += __shfl_xor(s, 16); s += __shfl_xor(s, 32);
        q += __shfl_xor(q, 16); q += __shfl_xor(q, 32);
        if (kseg == 0) { wsum[wave][col] = s; wsq[wave][col] = q; }
    }
    __syncthreads();
    if (tid < 64) {
        float S = wsum[0][tid] + wsum[1][tid] + wsum[2][tid] + wsum[3][tid];
        float Q = wsq[0][tid] + wsq[1][tid] + wsq[2][tid] + wsq[3][tid];
        atomicAdd(&sum1[tid], S);
        atomicAdd(&sq1[tid], Q);
    }
}

// h1 = relu(BN1(y1)) (bf16); y2 = h1 @ W2 + b2; fused column stats.
__global__ __launch_bounds__(256) void gemm2_mfma_kernel(
    const float* __restrict__ y1, const float* __restrict__ sum1, const float* __restrict__ sq1,
    const float* __restrict__ g1, const float* __restrict__ be1,
    const unsigned short* __restrict__ W2T, const float* __restrict__ b2,
    float* __restrict__ y2, float* __restrict__ sum2, float* __restrict__ sq2, int N) {
    __shared__ float sc[64], sh[64];
    __shared__ float wsum[4][64], wsq[4][64];
    int tid = threadIdx.x;
    if (tid < 64) {
        float invN = 1.0f / (float)N;
        float mu = sum1[tid] * invN;
        float var = sq1[tid] * invN - mu * mu;
        float rs = rsqrtf(var + EPS);
        float s = rs * g1[tid];
        sc[tid] = s;
        sh[tid] = be1[tid] - mu * s;
    }
    __syncthreads();
    int wave = tid >> 6, lane = tid & 63;
    int lrow = lane & 15, kseg = lane >> 4;
    int rbase = blockIdx.x * 64 + wave * 16;

    bf16x8 bfr[4][2];
#pragma unroll
    for (int nt = 0; nt < 4; ++nt)
#pragma unroll
        for (int kb = 0; kb < 2; ++kb)
            bfr[nt][kb] = *(const bf16x8*)(W2T + (size_t)(nt * 16 + lrow) * 64 + kb * 32 + kseg * 8);

    int r = rbase + lrow;
    size_t ro = (size_t)((r < N) ? r : 0) * HDIM;
    bf16x8 afr[2];
#pragma unroll
    for (int kb = 0; kb < 2; ++kb) {
        const f4v* yp = (const f4v*)(y1 + ro + kb * 32 + kseg * 8);
        f4v u0 = yp[0], u1 = yp[1];
        int k0 = kb * 32 + kseg * 8;
        bf16x8 a;
#pragma unroll
        for (int j = 0; j < 4; ++j) {
            float h0 = fmaxf(fmaf(u0[j], sc[k0 + j], sh[k0 + j]), 0.f);
            float h1 = fmaxf(fmaf(u1[j], sc[k0 + 4 + j], sh[k0 + 4 + j]), 0.f);
            a[j] = (short)bf16rn(h0);
            a[4 + j] = (short)bf16rn(h1);
        }
        afr[kb] = a;
    }

    f32x4 acc[4] = {};
#pragma unroll
    for (int kb = 0; kb < 2; ++kb)
#pragma unroll
        for (int nt = 0; nt < 4; ++nt)
            acc[nt] = __builtin_amdgcn_mfma_f32_16x16x32_bf16(afr[kb], bfr[nt][kb], acc[nt], 0, 0, 0);

#pragma unroll
    for (int nt = 0; nt < 4; ++nt) {
        int col = nt * 16 + lrow;
        float bias = b2[col];
        float s = 0.f, q = 0.f;
#pragma unroll
        for (int rr = 0; rr < 4; ++rr) {
            int rowi = rbase + kseg * 4 + rr;
            if (rowi < N) {
                float v = acc[nt][rr] + bias;
                y2[(size_t)rowi * HDIM + col] = v;
                s += v; q += v * v;
            }
        }
        s += __shfl_xor(s, 16); s += __shfl_xor(s, 32);
        q += __shfl_xor(q, 16); q += __shfl_xor(q, 32);
        if (kseg == 0) { wsum[wave][col] = s; wsq[wave][col] = q; }
    }
    __syncthreads();
    if (tid < 64) {
        float S = wsum[0][tid] + wsum[1][tid] + wsum[2][tid] + wsum[3][tid];
        float Q = wsq[0][tid] + wsq[1][tid] + wsq[2][tid] + wsq[3][tid];
        atomicAdd(&sum2[tid], S);
        atomicAdd(&sq2[tid], Q);
    }
}

// h2 = relu(BN2(y2)); att = sigmoid(h2 @ Wa + ba)
__global__ __launch_bounds__(256) void final_kernel(
    const float* __restrict__ y2, const float* __restrict__ sum2, const float* __restrict__ sq2,
    const float* __restrict__ g2, const float* __restrict__ be2,
    const float* __restrict__ Wa, const float* __restrict__ ba,
    float* __restrict__ out_h2, float* __restrict__ out_att, int N) {
    __shared__ float sc[HDIM], sh[HDIM], wa[HDIM];
    __shared__ float bav;
    if (threadIdx.x < HDIM) {
        int c = threadIdx.x;
        float invN = 1.0f / (float)N;
        float mu = sum2[c] * invN;
        float var = sq2[c] * invN - mu * mu;
        float rstd = rsqrtf(var + EPS);
        float s = rstd * g2[c];
        sc[c] = s;
        sh[c] = be2[c] - mu * s;
        wa[c] = Wa[c];
    }
    if (threadIdx.x == 0) bav = ba[0];
    __syncthreads();
    int n = blockIdx.x * 256 + threadIdx.x;
    if (n >= N) return;

    const f4v* p = (const f4v*)&y2[(size_t)n * HDIM];
    f4v* dst = (f4v*)&out_h2[(size_t)n * HDIM];
    float att = bav;
#pragma unroll 1
    for (int kk = 0; kk < 16; ++kk) {
        f4v u = p[kk];
        f4v hv;
#pragma unroll
        for (int j = 0; j < 4; ++j) {
            int k = kk * 4 + j;
            float h = fmaxf(fmaf(u[j], sc[k], sh[k]), 0.0f);
            hv[j] = h;
            att = fmaf(h, wa[k], att);
        }
        dst[kk] = hv;
    }
    out_att[n] = 1.0f / (1.0f + expf(-att));
}

extern "C" void kernel_launch(void* const* d_in, const int* in_sizes, int n_in,
                              void* d_out, int out_size, void* d_ws, size_t ws_size,
                              hipStream_t stream) {
    const int*   ei   = (const int*)d_in[1];
    const float* msg  = (const float*)d_in[2];
    const float* W1   = (const float*)d_in[3];
    const float* b1   = (const float*)d_in[4];
    const float* g1   = (const float*)d_in[5];
    const float* be1  = (const float*)d_in[6];
    const float* W2   = (const float*)d_in[7];
    const float* b2   = (const float*)d_in[8];
    const float* g2   = (const float*)d_in[9];
    const float* be2  = (const float*)d_in[10];
    const float* Wa   = (const float*)d_in[11];
    const float* ba   = (const float*)d_in[12];

    const int N = in_sizes[0] / HDIM;
    const int E = in_sizes[1] / 2;
    const int nblk = (N + BN - 1) / BN;

    // workspace layout
    unsigned short* fwdB = (unsigned short*)d_ws;                 // N*64 bf16
    unsigned short* bwdB = fwdB + (size_t)N * HDIM;               // N*64 bf16
    unsigned short* W1T  = bwdB + (size_t)N * HDIM;               // 8192 bf16
    unsigned short* W2T  = W1T + 8192;                            // 4096 bf16
    float*    stats      = (float*)(W2T + 4096);                  // 256 f32
    unsigned* bcur       = (unsigned*)(stats + 256);              // 2*nblk*NXCD*CURPAD u32
    unsigned* entries    = bcur + (size_t)2 * nblk * NXCD * CURPAD; // 2*nblk*NXCD*BCAPX u32
    unsigned short* msgB = (unsigned short*)(entries + (size_t)2 * nblk * NXCD * BCAPX); // E*64 u16
    float*    y1         = (float*)d_out;                         // staged in h2 region
    float*    y2         = (float*)d_ws;                          // overlays fwdB+bwdB exactly
    float*    out_att    = (float*)d_out + (size_t)N * HDIM;

    // zero stats + bucket cursors (contiguous)
    hipMemsetAsync(stats, 0, 256 * sizeof(float)
                             + (size_t)2 * nblk * NXCD * CURPAD * sizeof(unsigned), stream);

    int cblocks = (int)(((size_t)E * HDIM / 8 + 255) / 256);   // convert blocks
    int eblocks = (E + 255) / 256;                             // fill blocks
    int wblocks = 48;                                          // W prep blocks
    prep_kernel<<<cblocks + eblocks + wblocks, 256, 0, stream>>>(
        msg, msgB, ei, bcur, entries, W1, W2, W1T, W2T, E, nblk, cblocks, eblocks);

    binned_max_kernel<<<2 * nblk, 256, 0, stream>>>(msgB, bcur, entries, fwdB, bwdB, N, nblk);

    int G = (N + 63) / 64;
    gemm1_mfma_kernel<<<G, 256, 0, stream>>>(fwdB, bwdB, W1T, b1, y1,
                                             stats, stats + 64, N);
    gemm2_mfma_kernel<<<G, 256, 0, stream>>>(y1, stats, stats + 64, g1, be1,
                                             W2T, b2, y2, stats + 128, stats + 192, N);
    final_kernel<<<(N + 255) / 256, 256, 0, stream>>>(y2, stats + 128, stats + 192,
                                                      g2, be2, Wa, ba,
                                                      (float*)d_out, out_att, N);
}